// Round 4
// baseline (584.743 us; speedup 1.0000x reference)
//
#include <hip/hip_runtime.h>
#include <math.h>

// ---- problem constants (fixed shapes) ----
#define NPTS 16384
#define DIM  512
#define KSEL 11                   // K+1 smallest incl. self; min dropped at the end
#define NSPLIT 4
#define CPS   (NPTS / NSPLIT)     // 4096 columns per split
#define BM    256                 // rows per block (8 waves x 32 rows)
#define BN    32                  // columns staged per iteration (32 KB)
#define NITB  (CPS / BN)          // 128 phase-B iterations
#define NITA  16                  // phase-A sample: 512 cols -> threshold
#define ROWBYTES 1024             // DIM * 2 bytes (bf16)
#define NBUF  3                   // triple buffer for counted-vmcnt pipeline

typedef __attribute__((ext_vector_type(4))) float f32x4;
typedef __attribute__((ext_vector_type(8))) short s16x8;

__device__ __forceinline__ unsigned short f2bf(float f) {
    unsigned int x = __float_as_uint(f);
    return (unsigned short)((x + 0x7FFFu + ((x >> 16) & 1u)) >> 16);
}

__device__ __forceinline__ void gload_lds16(const void* g, void* l) {
    __builtin_amdgcn_global_load_lds(
        (const __attribute__((address_space(1))) void*)g,
        (__attribute__((address_space(3))) void*)l, 16, 0, 0);
}
__device__ __forceinline__ void gload_lds4(const void* g, void* l) {
    __builtin_amdgcn_global_load_lds(
        (const __attribute__((address_space(1))) void*)g,
        (__attribute__((address_space(3))) void*)l, 4, 0, 0);
}

__device__ __forceinline__ void pinreg(s16x8& v) { asm volatile("" : "+v"(v)); }

// scalar exact top-KSEL (smallest) scan over v[0..n); result in a[KSEL]; returns 11th smallest
__device__ __forceinline__ float topk_scan(const float* v, int n, float* a) {
    #pragma unroll
    for (int p = 0; p < KSEL; ++p) a[p] = v[p];
    float mx = a[0];
    #pragma unroll
    for (int p = 1; p < KSEL; ++p) mx = fmaxf(mx, a[p]);
    for (int i = KSEL; i < n; ++i) {
        const float x = v[i];
        if (x < mx) {
            bool done = false;
            #pragma unroll
            for (int p = 0; p < KSEL; ++p) {
                const bool rep = (!done) && (a[p] == mx);
                a[p] = rep ? x : a[p];
                done = done || rep;
            }
            mx = a[0];
            #pragma unroll
            for (int p = 1; p < KSEL; ++p) mx = fmaxf(mx, a[p]);
        }
    }
    return mx;
}

// ---- kernel 1: fp32 -> bf16, XOR-swizzled: byte = row*1024 + ((kb*16) ^ ((row&7)<<4))
__global__ void prep_convert(const float* __restrict__ obs, char* __restrict__ obsb) {
    const int t   = blockIdx.x * 256 + threadIdx.x;
    const int row = t >> 6;
    const int kb  = t & 63;
    const float4* s = (const float4*)(obs + (unsigned long)row * DIM + kb * 8);
    const float4 a = s[0], b = s[1];
    uint4 o;
    o.x = (unsigned int)f2bf(a.x) | ((unsigned int)f2bf(a.y) << 16);
    o.y = (unsigned int)f2bf(a.z) | ((unsigned int)f2bf(a.w) << 16);
    o.z = (unsigned int)f2bf(b.x) | ((unsigned int)f2bf(b.y) << 16);
    o.w = (unsigned int)f2bf(b.z) | ((unsigned int)f2bf(b.w) << 16);
    *(uint4*)(obsb + (unsigned long)row * ROWBYTES + ((kb * 16) ^ ((row & 7) << 4))) = o;
}

// ---- kernel 2: sq[i] = ||x_i||^2 in fp32
__global__ void prep_sq(const float* __restrict__ obs, float* __restrict__ sq) {
    const int wv = threadIdx.x >> 6, ln = threadIdx.x & 63;
    const int row = blockIdx.x * 4 + wv;
    const float4* p = (const float4*)(obs + (unsigned long)row * DIM + ln * 8);
    const float4 a = p[0], b = p[1];
    float s = a.x*a.x + a.y*a.y + a.z*a.z + a.w*a.w
            + b.x*b.x + b.y*b.y + b.z*b.z + b.w*b.w;
    #pragma unroll
    for (int o = 32; o; o >>= 1) s += __shfl_xor(s, o);
    if (ln == 0) sq[row] = s;
}

// ---- kernel 3: two-phase fused distance GEMM + exact per-row top-11
//   3-deep pipelined (counted vmcnt, never drained in-loop), 4 sub-phases/iter.
__global__ __launch_bounds__(512, 2) void knn_main(
    const char* __restrict__ obsb, const float* __restrict__ sq,
    float* __restrict__ cand)
{
    __shared__ __align__(16) char Braw[NBUF][BN * ROWBYTES];   // 96 KB
    __shared__ float sqs[NBUF][64];
    __shared__ float Trow[BM];

    const int tid = threadIdx.x;
    const int wv = tid >> 6, ln = tid & 63;
    // XCD-bijective swizzle: 256 blocks, 8 XCDs -> each XCD owns 32 consecutive
    // row-tiles of ONE split => shared 4MB column panel fits that XCD's L2.
    const int bid = blockIdx.x;
    const int swz = (bid & 7) * 32 + (bid >> 3);
    const int sp = swz >> 6;                 // split 0..3
    const int rt = swz & 63;                 // row tile 0..63
    const int R0 = rt * BM;
    const int C0 = sp * CPS;
    const int wrow0 = R0 + wv * 32;
    const int lr = ln & 15;                  // row within 16-row strip
    const int kc = ln >> 4;                  // k-chunk 0..3

    // A fragments (row points): load once, pinned (lives in unified VGPR/AGPR file)
    s16x8 afrag[2][16];
    float sqr[2];
    #pragma unroll
    for (int s = 0; s < 2; ++s) {
        const int row = wrow0 + s * 16 + lr;
        const unsigned long rb = (unsigned long)row * ROWBYTES;
        const int kxA = (kc << 4) ^ ((row & 7) << 4);
        #pragma unroll
        for (int t = 0; t < 16; ++t) {
            afrag[s][t] = *(const s16x8*)(obsb + rb + ((t * 64) ^ kxA));
            pinreg(afrag[s][t]);
        }
        sqr[s] = sq[row];
    }

    // LDS read bases for column frags: addr = bse[cg][t&1] + (t>>1)*128
    int bse[2][2];
    #pragma unroll
    for (int cg = 0; cg < 2; ++cg) {
        const int colL = cg * 16 + lr;
        const int s7 = (colL & 7) << 4;
        const int kxlow = (kc << 4) ^ (s7 & 0x30);
        const int b6 = (s7 >> 6) & 1;
        bse[cg][0] = colL * ROWBYTES + kxlow + (b6 << 6);
        bse[cg][1] = colL * ROWBYTES + kxlow + ((1 ^ b6) << 6);
    }

    // per-wave stage: 4 x 1KB columns + 1 sq tile => exactly 5 vmem ops/iter/wave
#define STG_B(NB, CIT, P) gload_lds16(                                          \
        obsb + (unsigned long)(C0 + (CIT) * BN) * ROWBYTES + wv * 4096          \
             + (P) * 1024 + ln * 16,                                            \
        &Braw[NB][0] + wv * 4096 + (P) * 1024)
#define STG_SQ(NB, CIT) gload_lds4(sq + C0 + (CIT) * BN + (ln & 31), &sqs[NB][0])
#define STAGE_FULL(NB, CIT) do {                                                \
        STG_B(NB, CIT, 0); STG_B(NB, CIT, 1);                                   \
        STG_B(NB, CIT, 2); STG_B(NB, CIT, 3); STG_SQ(NB, CIT);                  \
    } while (0)

#define MFMA_Q(CGJ, TT)                                                          \
        acc[0][CGJ] = __builtin_amdgcn_mfma_f32_16x16x32_bf16(b[CGJ], afrag[0][TT], acc[0][CGJ], 0, 0, 0); \
        acc[1][CGJ] = __builtin_amdgcn_mfma_f32_16x16x32_bf16(b[CGJ], afrag[1][TT], acc[1][CGJ], 0, 0, 0);

    // one sub-phase: 8 ds_read_b128 + 1 staged column + barrier + 16 MFMA
#define PH(P, DOST, NB, CIT2, EXTRA) do {                                        \
        s16x8 b[2];                                                              \
        s16x8 c0a = *(const s16x8*)(bpR + bse[0][0] + (2*(P))*128);              \
        s16x8 c1a = *(const s16x8*)(bpR + bse[1][0] + (2*(P))*128);              \
        s16x8 c0b = *(const s16x8*)(bpR + bse[0][1] + (2*(P))*128);              \
        s16x8 c1b = *(const s16x8*)(bpR + bse[1][1] + (2*(P))*128);              \
        s16x8 c0c = *(const s16x8*)(bpR + bse[0][0] + (2*(P)+1)*128);            \
        s16x8 c1c = *(const s16x8*)(bpR + bse[1][0] + (2*(P)+1)*128);            \
        s16x8 c0d = *(const s16x8*)(bpR + bse[0][1] + (2*(P)+1)*128);            \
        s16x8 c1d = *(const s16x8*)(bpR + bse[1][1] + (2*(P)+1)*128);            \
        if (DOST) { STG_B(NB, CIT2, P); EXTRA; }                                 \
        __builtin_amdgcn_s_barrier();                                            \
        __builtin_amdgcn_s_setprio(1);                                           \
        b[0] = c0a; b[1] = c1a; MFMA_Q(0, 4*(P)+0); MFMA_Q(1, 4*(P)+0);          \
        b[0] = c0b; b[1] = c1b; MFMA_Q(0, 4*(P)+1); MFMA_Q(1, 4*(P)+1);          \
        b[0] = c0c; b[1] = c1c; MFMA_Q(0, 4*(P)+2); MFMA_Q(1, 4*(P)+2);          \
        b[0] = c0d; b[1] = c1d; MFMA_Q(0, 4*(P)+3); MFMA_Q(1, 4*(P)+3);          \
        __builtin_amdgcn_s_setprio(0);                                           \
    } while (0)

#define GEMM_ITER(NIT)                                                           \
        const int cit2 = it + 2;                                                 \
        const bool dost = cit2 < (NIT);                                          \
        const char* bpR = &Braw[0][0] + bR * (BN * ROWBYTES);                    \
        f32x4 acc[2][2] = {{{0.f,0.f,0.f,0.f},{0.f,0.f,0.f,0.f}},                \
                           {{0.f,0.f,0.f,0.f},{0.f,0.f,0.f,0.f}}};               \
        PH(0, dost, bS, cit2, (void)0);                                          \
        PH(1, dost, bS, cit2, (void)0);                                          \
        PH(2, dost, bS, cit2, (void)0);                                          \
        PH(3, dost, bS, cit2, STG_SQ(bS, cit2));                                 \
        const f32x4 sqv0 = *(const f32x4*)&sqs[bR][kc * 4];                      \
        const f32x4 sqv1 = *(const f32x4*)&sqs[bR][16 + kc * 4];

#define BOUNDARY(NIT) do {                                                       \
        if (it < (NIT) - 2) asm volatile("s_waitcnt vmcnt(5)" ::: "memory");     \
        else                asm volatile("s_waitcnt vmcnt(0)" ::: "memory");     \
        __builtin_amdgcn_s_barrier();                                            \
        const int tb_ = bR; bR = bM; bM = bS; bS = tb_;                          \
    } while (0)

#define DIST(S, CG, R) fmaf(-2.0f, acc[S][CG][R], sqr[S] + (CG ? sqv1[R] : sqv0[R]))

    // ================= phase A: slot minima over 512 sampled cols =================
    float segmin[2][8];
    #pragma unroll
    for (int s = 0; s < 2; ++s)
        #pragma unroll
        for (int q = 0; q < 8; ++q) segmin[s][q] = __builtin_inff();

    int bR = 0, bM = 1, bS = 2;
    STAGE_FULL(0, 0);
    STAGE_FULL(1, 1);
    asm volatile("s_waitcnt vmcnt(5)" ::: "memory");
    __builtin_amdgcn_s_barrier();

    for (int it = 0; it < NITA; ++it) {
        GEMM_ITER(NITA);
        #pragma unroll
        for (int s = 0; s < 2; ++s)
            #pragma unroll
            for (int cg = 0; cg < 2; ++cg)
                #pragma unroll
                for (int r = 0; r < 4; ++r)
                    segmin[s][cg * 4 + r] = fminf(segmin[s][cg * 4 + r], DIST(s, cg, r));
        BOUNDARY(NITA);
    }

    // gather 32 slot-minima per row (stride 33) -> T (valid upper bound of row 11th)
    __syncthreads();
    float* mins = (float*)&Braw[0][0];               // [BM][33]
    #pragma unroll
    for (int s = 0; s < 2; ++s)
        #pragma unroll
        for (int q = 0; q < 8; ++q)
            mins[(wv * 32 + s * 16 + lr) * 33 + kc * 8 + q] = segmin[s][q];
    __syncthreads();
    if (tid < BM) {
        float a[KSEL];
        Trow[tid] = topk_scan(mins + tid * 33, 32, a);
    }
    __syncthreads();

    // ================= phase B: seeded per-lane register heaps =================
    float hp[2][KSEL], hmax[2], mxv[2], tseed[2];
    #pragma unroll
    for (int s = 0; s < 2; ++s) {
        #pragma unroll
        for (int p = 0; p < KSEL; ++p) hp[s][p] = __builtin_inff();
        hmax[s]  = __builtin_inff();
        tseed[s] = Trow[wv * 32 + s * 16 + lr] + 1e-3f;
        mxv[s]   = tseed[s];
    }
    __syncthreads();

#define INS(S, VV) do {                                                         \
        if (__any((VV) < mxv[S])) {                                             \
            const bool ins_ = (VV) < mxv[S];                                    \
            bool done_ = !ins_;                                                 \
            _Pragma("unroll")                                                   \
            for (int p = 0; p < KSEL; ++p) {                                    \
                const bool rep_ = (!done_) && (hp[S][p] == hmax[S]);            \
                hp[S][p] = rep_ ? (VV) : hp[S][p];                              \
                done_ = done_ || rep_;                                          \
            }                                                                   \
            float m_ = hp[S][0];                                                \
            _Pragma("unroll")                                                   \
            for (int p = 1; p < KSEL; ++p) m_ = fmaxf(m_, hp[S][p]);            \
            hmax[S] = m_;                                                       \
            mxv[S]  = fminf(tseed[S], m_);                                      \
        }                                                                       \
    } while (0)

#define PHASEB_STRIP(S) do {                                                    \
        const float w0 = DIST(S,0,0), w1 = DIST(S,0,1), w2 = DIST(S,0,2), w3 = DIST(S,0,3); \
        const float w4 = DIST(S,1,0), w5 = DIST(S,1,1), w6 = DIST(S,1,2), w7 = DIST(S,1,3); \
        INS(S,w0); INS(S,w1); INS(S,w2); INS(S,w3);                             \
        INS(S,w4); INS(S,w5); INS(S,w6); INS(S,w7);                             \
    } while (0)

    bR = 0; bM = 1; bS = 2;
    STAGE_FULL(0, 0);
    STAGE_FULL(1, 1);
    asm volatile("s_waitcnt vmcnt(5)" ::: "memory");
    __builtin_amdgcn_s_barrier();

    for (int it = 0; it < NITB; ++it) {
        GEMM_ITER(NITB);
        PHASEB_STRIP(0);
        PHASEB_STRIP(1);
        BOUNDARY(NITB);
    }

    // merge 4 lanes x 11 per row -> exact top-11 of this split (stride 45)
    __syncthreads();
    float* sc2 = (float*)&Braw[0][0];                // [BM][45] = 45 KB
    #pragma unroll
    for (int s = 0; s < 2; ++s)
        #pragma unroll
        for (int p = 0; p < KSEL; ++p)
            sc2[(wv * 32 + s * 16 + lr) * 45 + kc * KSEL + p] = hp[s][p];
    __syncthreads();
    if (tid < BM) {
        float a[KSEL];
        topk_scan(sc2 + tid * 45, 44, a);
        #pragma unroll
        for (int p = 0; p < KSEL; ++p)
            cand[(unsigned long)(R0 + tid) * (NSPLIT * KSEL) + sp * KSEL + p] = a[p];
    }
}

// ---- kernel 4: merge 4x11 split candidates per row -> output
__global__ void merge_out(const float* __restrict__ cand, float* __restrict__ out) {
    const int row = blockIdx.x * 256 + threadIdx.x;
    const float* c = cand + (unsigned long)row * (NSPLIT * KSEL);
    float arr[KSEL];
    topk_scan(c, NSPLIT * KSEL, arr);
    float mn = arr[0];
    #pragma unroll
    for (int q = 1; q < KSEL; ++q) mn = fminf(mn, arr[q]);
    float ssum = 0.f;
    #pragma unroll
    for (int q = 0; q < KSEL; ++q) ssum += sqrtf(fmaxf(arr[q], 0.f));
    out[row] = log1pf((ssum - sqrtf(fmaxf(mn, 0.f))) * 0.1f);
}

extern "C" void kernel_launch(void* const* d_in, const int* in_sizes, int n_in,
                              void* d_out, int out_size, void* d_ws, size_t ws_size,
                              hipStream_t stream) {
    const float* obs = (const float*)d_in[0];
    float* out = (float*)d_out;
    char* ws = (char*)d_ws;

    char*  obsb = ws;                                        // 16 MB swizzled bf16
    float* sq   = (float*)(ws + (size_t)NPTS * ROWBYTES);    // 64 KB
    float* cand = (float*)(ws + (size_t)NPTS * ROWBYTES + NPTS * sizeof(float)); // ~2.9 MB

    prep_convert<<<NPTS * 64 / 256, 256, 0, stream>>>(obs, obsb);
    prep_sq<<<NPTS / 4, 256, 0, stream>>>(obs, sq);
    knn_main<<<(NPTS / BM) * NSPLIT, 512, 0, stream>>>(obsb, sq, cand);  // 256 blocks
    merge_out<<<NPTS / 256, 256, 0, stream>>>(cand, out);
}

// Round 5
// 515.994 us; speedup vs baseline: 1.1332x; 1.1332x over previous
//
#include <hip/hip_runtime.h>
#include <math.h>

// ---- problem constants (fixed shapes) ----
#define NPTS 16384
#define DIM  512
#define KSEL 11                   // K+1 smallest incl. self; min dropped at the end
#define NSPLIT 4
#define CPS   (NPTS / NSPLIT)     // 4096 columns per split
#define BM    128                 // rows per block (4 waves x 32 rows)
#define BN    32                  // columns staged per iteration (32 KB)
#define ITERS (CPS / BN)          // 128 phase-B iterations
#define SAMPLE_ITERS 16           // phase A: threshold from first 512 cols of split
#define ROWBYTES 1024             // DIM * 2 bytes (bf16)

typedef __attribute__((ext_vector_type(4))) float f32x4;
typedef __attribute__((ext_vector_type(8))) short s16x8;

__device__ __forceinline__ unsigned short f2bf(float f) {
    unsigned int x = __float_as_uint(f);
    return (unsigned short)((x + 0x7FFFu + ((x >> 16) & 1u)) >> 16);
}

__device__ __forceinline__ void gload_lds16(const void* g, void* l) {
    __builtin_amdgcn_global_load_lds(
        (const __attribute__((address_space(1))) void*)g,
        (__attribute__((address_space(3))) void*)l, 16, 0, 0);
}

// pin a loaded fragment: value becomes opaque -> compiler cannot rematerialize
__device__ __forceinline__ void pinreg(s16x8& v) { asm volatile("" : "+v"(v)); }

// scalar exact top-KSEL (smallest) scan over v[0..n); result in a[KSEL]; returns 11th smallest
__device__ __forceinline__ float topk_scan(const float* v, int n, float* a) {
    #pragma unroll
    for (int p = 0; p < KSEL; ++p) a[p] = v[p];
    float mx = a[0];
    #pragma unroll
    for (int p = 1; p < KSEL; ++p) mx = fmaxf(mx, a[p]);
    for (int i = KSEL; i < n; ++i) {
        const float x = v[i];
        if (x < mx) {
            bool done = false;
            #pragma unroll
            for (int p = 0; p < KSEL; ++p) {
                const bool rep = (!done) && (a[p] == mx);
                a[p] = rep ? x : a[p];
                done = done || rep;
            }
            mx = a[0];
            #pragma unroll
            for (int p = 1; p < KSEL; ++p) mx = fmaxf(mx, a[p]);
        }
    }
    return mx;
}

// ---- kernel 1: fused fp32->bf16 swizzled convert + ||x_i||^2
//   one wave per row: lane ln owns elems [ln*8, ln*8+8)
//   swizzle: byte = row*1024 + ((ln*16) ^ ((row&7)<<4))
__global__ void prep_convert(const float* __restrict__ obs, char* __restrict__ obsb,
                             float* __restrict__ sq) {
    const int wv = threadIdx.x >> 6, ln = threadIdx.x & 63;
    const int row = blockIdx.x * 4 + wv;
    const float4* s = (const float4*)(obs + (unsigned long)row * DIM + ln * 8);
    const float4 a = s[0], b = s[1];
    uint4 o;
    o.x = (unsigned int)f2bf(a.x) | ((unsigned int)f2bf(a.y) << 16);
    o.y = (unsigned int)f2bf(a.z) | ((unsigned int)f2bf(a.w) << 16);
    o.z = (unsigned int)f2bf(b.x) | ((unsigned int)f2bf(b.y) << 16);
    o.w = (unsigned int)f2bf(b.z) | ((unsigned int)f2bf(b.w) << 16);
    *(uint4*)(obsb + (unsigned long)row * ROWBYTES + ((ln * 16) ^ ((row & 7) << 4))) = o;
    float ss = a.x*a.x + a.y*a.y + a.z*a.z + a.w*a.w
             + b.x*b.x + b.y*b.y + b.z*b.z + b.w*b.w;
    #pragma unroll
    for (int off = 32; off; off >>= 1) ss += __shfl_xor(ss, off);
    if (ln == 0) sq[row] = ss;
}

// ---- kernel 2: two-phase fused distance GEMM + exact per-row top-11
__global__ __launch_bounds__(256, 2) void knn_main(
    const char* __restrict__ obsb, const float* __restrict__ sq,
    float* __restrict__ cand)
{
    __shared__ __align__(16) char Braw[2][BN * ROWBYTES];   // 64 KB double buffer
    __shared__ float Trow[BM];

    const int tid = threadIdx.x;
    const int wv = tid >> 6, ln = tid & 63;
    const int sp = blockIdx.x >> 7;          // split 0..3
    const int rt = blockIdx.x & 127;         // row tile 0..127
    const int R0 = rt * BM;
    const int C0 = sp * CPS;
    const int wrow0 = R0 + wv * 32;
    const int lr = ln & 15;                  // row within strip
    const int kc = ln >> 4;                  // k-chunk 0..3

    // A fragments (row points): load once, pin in registers for both phases
    s16x8 afrag[2][16];
    float sqr[2];
    #pragma unroll
    for (int s = 0; s < 2; ++s) {
        const int row = wrow0 + s * 16 + lr;
        const unsigned long rb = (unsigned long)row * ROWBYTES;
        const int kxA = (kc << 4) ^ ((row & 7) << 4);
        #pragma unroll
        for (int t = 0; t < 16; ++t) {
            afrag[s][t] = *(const s16x8*)(obsb + rb + ((t * 64) ^ kxA));
            pinreg(afrag[s][t]);
        }
        sqr[s] = sq[row];
    }

    // LDS read bases for column frags: addr = bse[cg][t&1] + (t>>1)*128
    int bse[2][2];
    #pragma unroll
    for (int cg = 0; cg < 2; ++cg) {
        const int colL = cg * 16 + lr;
        const int s7 = (colL & 7) << 4;
        const int kxlow = (kc << 4) ^ (s7 & 0x30);
        const int b6 = (s7 >> 6) & 1;
        bse[cg][0] = colL * ROWBYTES + kxlow + (b6 << 6);
        bse[cg][1] = colL * ROWBYTES + kxlow + ((1 ^ b6) << 6);
    }

#define STAGE(BUF, CITER) do {                                                  \
        const char* gs_ = obsb + (unsigned long)(C0 + (CITER) * BN) * ROWBYTES  \
                          + wv * 1024 + ln * 16;                                \
        char* lb_ = &Braw[BUF][0] + wv * 1024;                                  \
        _Pragma("unroll")                                                       \
        for (int r_ = 0; r_ < 8; ++r_)                                          \
            gload_lds16(gs_ + r_ * 4096, lb_ + r_ * 4096);                      \
    } while (0)

#define GEMM_BODY(CUR, CITER)                                                   \
        const char* bp = &Braw[CUR][0];                                         \
        f32x4 acc[2][2] = {{{0.f,0.f,0.f,0.f},{0.f,0.f,0.f,0.f}},               \
                           {{0.f,0.f,0.f,0.f},{0.f,0.f,0.f,0.f}}};              \
        _Pragma("unroll")                                                       \
        for (int cg = 0; cg < 2; ++cg) {                                        \
            _Pragma("unroll")                                                   \
            for (int t = 0; t < 16; ++t) {                                      \
                const s16x8 b = *(const s16x8*)(bp + bse[cg][t & 1] + (t >> 1) * 128); \
                acc[0][cg] = __builtin_amdgcn_mfma_f32_16x16x32_bf16(b, afrag[0][t], acc[0][cg], 0, 0, 0); \
                acc[1][cg] = __builtin_amdgcn_mfma_f32_16x16x32_bf16(b, afrag[1][t], acc[1][cg], 0, 0, 0); \
            }                                                                   \
        }                                                                       \
        f32x4 sqv[2];                                                           \
        sqv[0] = *(const f32x4*)(sq + C0 + (CITER) * BN + kc * 4);              \
        sqv[1] = *(const f32x4*)(sq + C0 + (CITER) * BN + 16 + kc * 4);

#define DIST(S, CG, R) fmaf(-2.0f, acc[S][CG][R], sqr[S] + sqv[CG][R])

    // ================= phase A: slot minima over sampled 512 cols =================
    float segmin[2][8];
    #pragma unroll
    for (int s = 0; s < 2; ++s)
        #pragma unroll
        for (int q = 0; q < 8; ++q) segmin[s][q] = __builtin_inff();

    STAGE(0, 0);
    __syncthreads();
    #pragma unroll 2
    for (int it = 0; it < SAMPLE_ITERS; ++it) {
        const int cur = it & 1;
        if (it + 1 < SAMPLE_ITERS) STAGE(cur ^ 1, it + 1);
        GEMM_BODY(cur, it);
        #pragma unroll
        for (int s = 0; s < 2; ++s)
            #pragma unroll
            for (int cg = 0; cg < 2; ++cg)
                #pragma unroll
                for (int r = 0; r < 4; ++r)
                    segmin[s][cg * 4 + r] = fminf(segmin[s][cg * 4 + r], DIST(s, cg, r));
        __syncthreads();
    }

    // gather 32 slot-minima per row (stride 33 to avoid bank conflicts) -> T
    // (T = 11th smallest of 32 ACTUAL distances at distinct columns => provable
    //  upper bound of the row's true 11th smallest; phase B re-computes all
    //  columns bit-identically, so the gate is exact.)
    float* mins = (float*)&Braw[0][0];               // [BM][33]
    #pragma unroll
    for (int s = 0; s < 2; ++s)
        #pragma unroll
        for (int q = 0; q < 8; ++q)
            mins[(wv * 32 + s * 16 + lr) * 33 + kc * 8 + q] = segmin[s][q];
    __syncthreads();
    if (tid < BM) {
        float a[KSEL];
        Trow[tid] = topk_scan(mins + tid * 33, 32, a);
    }
    __syncthreads();

    // ================= phase B: seeded per-lane register heaps =================
    float hp[2][KSEL], hmax[2], mxv[2], tseed[2];
    #pragma unroll
    for (int s = 0; s < 2; ++s) {
        #pragma unroll
        for (int p = 0; p < KSEL; ++p) hp[s][p] = __builtin_inff();
        hmax[s]  = __builtin_inff();
        tseed[s] = Trow[wv * 32 + s * 16 + lr] + 1e-3f;
        mxv[s]   = tseed[s];
    }
    __syncthreads();   // Trow read before Braw[0] re-staged below

#define INS(S, VV) do {                                                         \
        if (__any((VV) < mxv[S])) {                                             \
            const bool ins_ = (VV) < mxv[S];                                    \
            bool done_ = !ins_;                                                 \
            _Pragma("unroll")                                                   \
            for (int p = 0; p < KSEL; ++p) {                                    \
                const bool rep_ = (!done_) && (hp[S][p] == hmax[S]);            \
                hp[S][p] = rep_ ? (VV) : hp[S][p];                              \
                done_ = done_ || rep_;                                          \
            }                                                                   \
            float m_ = hp[S][0];                                                \
            _Pragma("unroll")                                                   \
            for (int p = 1; p < KSEL; ++p) m_ = fmaxf(m_, hp[S][p]);            \
            hmax[S] = m_;                                                       \
            mxv[S]  = fminf(tseed[S], m_);                                      \
        }                                                                       \
    } while (0)

#define PHASEB_STRIP(S) do {                                                    \
        const float w0 = DIST(S,0,0), w1 = DIST(S,0,1), w2 = DIST(S,0,2), w3 = DIST(S,0,3); \
        const float w4 = DIST(S,1,0), w5 = DIST(S,1,1), w6 = DIST(S,1,2), w7 = DIST(S,1,3); \
        INS(S,w0); INS(S,w1); INS(S,w2); INS(S,w3);                             \
        INS(S,w4); INS(S,w5); INS(S,w6); INS(S,w7);                             \
    } while (0)

    STAGE(0, 0);
    __syncthreads();
    #pragma unroll 2
    for (int it = 0; it < ITERS; ++it) {
        const int cur = it & 1;
        if (it + 1 < ITERS) STAGE(cur ^ 1, it + 1);
        GEMM_BODY(cur, it);
        PHASEB_STRIP(0);
        PHASEB_STRIP(1);
        __syncthreads();
    }

    // merge 4 lanes x 11 per row -> exact top-11 of this split (stride 45, pad)
    float* sc2 = (float*)&Braw[0][0];                // [BM][45]
    #pragma unroll
    for (int s = 0; s < 2; ++s)
        #pragma unroll
        for (int p = 0; p < KSEL; ++p)
            sc2[(wv * 32 + s * 16 + lr) * 45 + kc * KSEL + p] = hp[s][p];
    __syncthreads();
    if (tid < BM) {
        float a[KSEL];
        topk_scan(sc2 + tid * 45, 44, a);
        #pragma unroll
        for (int p = 0; p < KSEL; ++p)
            cand[(unsigned long)(R0 + tid) * (NSPLIT * KSEL) + sp * KSEL + p] = a[p];
    }
}

// ---- kernel 3: merge 4x11 split candidates per row -> output
__global__ void merge_out(const float* __restrict__ cand, float* __restrict__ out) {
    const int row = blockIdx.x * 256 + threadIdx.x;
    const float* c = cand + (unsigned long)row * (NSPLIT * KSEL);
    float arr[KSEL];
    topk_scan(c, NSPLIT * KSEL, arr);
    float mn = arr[0];
    #pragma unroll
    for (int q = 1; q < KSEL; ++q) mn = fminf(mn, arr[q]);
    float ssum = 0.f;
    #pragma unroll
    for (int q = 0; q < KSEL; ++q) ssum += sqrtf(fmaxf(arr[q], 0.f));
    out[row] = log1pf((ssum - sqrtf(fmaxf(mn, 0.f))) * 0.1f);
}

extern "C" void kernel_launch(void* const* d_in, const int* in_sizes, int n_in,
                              void* d_out, int out_size, void* d_ws, size_t ws_size,
                              hipStream_t stream) {
    const float* obs = (const float*)d_in[0];
    float* out = (float*)d_out;
    char* ws = (char*)d_ws;

    char*  obsb = ws;                                        // 16 MB swizzled bf16
    float* sq   = (float*)(ws + (size_t)NPTS * ROWBYTES);    // 64 KB
    float* cand = (float*)(ws + (size_t)NPTS * ROWBYTES + NPTS * sizeof(float)); // ~2.9 MB

    prep_convert<<<NPTS / 4, 256, 0, stream>>>(obs, obsb, sq);
    knn_main<<<(NPTS / BM) * NSPLIT, 256, 0, stream>>>(obsb, sq, cand);  // 512 blocks
    merge_out<<<NPTS / 256, 256, 0, stream>>>(cand, out);
}